// Round 4
// baseline (877.132 us; speedup 1.0000x reference)
//
#include <hip/hip_runtime.h>
#include <hip/hip_bf16.h>

// Problem constants
#define B_   4
#define C_   32
#define H_   192
#define W_   192
#define HW_  (H_ * W_)          // 36864 = 144 * 256
#define EPS_ 1e-5f

// BETA/ln2 and ln2/BETA (logsumexp in base 2 for the HW exp2/log2 pipe)
#define SCALE_IN  21.640425613334453f
#define SCALE_OUT 0.046209812037329687f

// ---------------------------------------------------------------------------
// Module-global scratch (no d_ws dependence).
//   g_stats[0..127]   sum1    [128..255] sq1
//   g_stats[256..287] sum2    [288..319] sq2
//   g_stats[320..447] sc1     [448..575] sh1
//   g_stats[576..607] sc2     [608..639] sh2
//   g_E  : erode output, bf16, layout (branch, b, c, p)
//   g_DY : shared D (dilate scratch, per branch) then Y (conv output)
// All fully re-initialized every kernel_launch -> deterministic.
// ---------------------------------------------------------------------------
__device__ float          g_stats[640];
__device__ __hip_bfloat16 g_E[(size_t)4 * B_ * C_ * HW_];   // 37.75 MB
__device__ float          g_DY[(size_t)B_ * C_ * HW_];      // 18.87 MB

__global__ void zero_k() {
    if (threadIdx.x < 640) g_stats[threadIdx.x] = 0.0f;
}

// ---------------------------------------------------------------------------
// soft dilate: D[b,c,p] = LSE_k( beta*(x_tap_k + wd_k) ) / beta
// tap k=(i,j): x[h+(i-1)*d, w+(j-1)*d], zero outside (zero padding)
// ---------------------------------------------------------------------------
__global__ __launch_bounds__(256) void dilate_k(const float* __restrict__ x,
                                                const float* __restrict__ wd,
                                                int branch) {
    const int d = branch + 1;
    const int p = blockIdx.x * 256 + threadIdx.x;     // 0..HW-1 exact
    const int c = blockIdx.y;
    const int b = blockIdx.z;
    const int h = p / W_;
    const int w = p - h * W_;

    const float* xp = x + (size_t)(b * C_ + c) * HW_;
    const float* wt = wd + (size_t)(branch * C_ + c) * 9;

    float t[9];
    float m = -1e30f;
#pragma unroll
    for (int i = 0; i < 3; i++) {
#pragma unroll
        for (int j = 0; j < 3; j++) {
            const int hh = h + (i - 1) * d;
            const int ww = w + (j - 1) * d;
            float xv = 0.0f;
            if (hh >= 0 && hh < H_ && ww >= 0 && ww < W_) xv = xp[hh * W_ + ww];
            const float v = (xv + wt[i * 3 + j]) * SCALE_IN;
            t[i * 3 + j] = v;
            m = fmaxf(m, v);
        }
    }
    float s = 0.0f;
#pragma unroll
    for (int k = 0; k < 9; k++) s += exp2f(t[k] - m);
    g_DY[(size_t)(b * C_ + c) * HW_ + p] = (m + log2f(s)) * SCALE_OUT;
}

// ---------------------------------------------------------------------------
// soft erode: E = -LSE_k( beta*(we_k - D_tap_k) ) / beta, + BN1 stats
// ---------------------------------------------------------------------------
__global__ __launch_bounds__(256) void erode_k(const float* __restrict__ we,
                                               int branch) {
    const int d = branch + 1;
    const int p = blockIdx.x * 256 + threadIdx.x;
    const int c = blockIdx.y;
    const int b = blockIdx.z;
    const int h = p / W_;
    const int w = p - h * W_;

    const float* Dp = g_DY + (size_t)(b * C_ + c) * HW_;
    const float* wt = we + (size_t)(branch * C_ + c) * 9;

    float t[9];
    float m = -1e30f;
#pragma unroll
    for (int i = 0; i < 3; i++) {
#pragma unroll
        for (int j = 0; j < 3; j++) {
            const int hh = h + (i - 1) * d;
            const int ww = w + (j - 1) * d;
            float dv = 0.0f;
            if (hh >= 0 && hh < H_ && ww >= 0 && ww < W_) dv = Dp[hh * W_ + ww];
            const float v = (wt[i * 3 + j] - dv) * SCALE_IN;
            t[i * 3 + j] = v;
            m = fmaxf(m, v);
        }
    }
    float s = 0.0f;
#pragma unroll
    for (int k = 0; k < 9; k++) s += exp2f(t[k] - m);
    const float val = -(m + log2f(s)) * SCALE_OUT;

    g_E[(((size_t)branch * B_ + b) * C_ + c) * HW_ + p] = __float2bfloat16(val);

    // per-block partial sum/sumsq for channel (branch, c), then one atomic
    float s1 = val;
    float s2 = val * val;
#pragma unroll
    for (int off = 32; off >= 1; off >>= 1) {
        s1 += __shfl_down(s1, off, 64);
        s2 += __shfl_down(s2, off, 64);
    }
    __shared__ float l1[4], l2[4];
    const int lane = threadIdx.x & 63;
    const int wv   = threadIdx.x >> 6;
    if (lane == 0) { l1[wv] = s1; l2[wv] = s2; }
    __syncthreads();
    if (threadIdx.x == 0) {
        atomicAdd(&g_stats[branch * C_ + c],       l1[0] + l1[1] + l1[2] + l1[3]);
        atomicAdd(&g_stats[128 + branch * C_ + c], l2[0] + l2[1] + l2[2] + l2[3]);
    }
}

// ---------------------------------------------------------------------------
// finalize BN1: per-channel scale/shift (128 channels)
// ---------------------------------------------------------------------------
__global__ void fin1_k(const float* __restrict__ gs, const float* __restrict__ bs) {
    const int i = threadIdx.x;
    if (i < 128) {
        const float N  = (float)(B_ * HW_);
        const float mu = g_stats[i] / N;
        const float va = fmaxf(g_stats[128 + i] / N - mu * mu, 0.0f);
        const float sc = gs[i] * rsqrtf(va + EPS_);
        g_stats[320 + i] = sc;
        g_stats[448 + i] = bs[i] - mu * sc;
    }
}

// ---------------------------------------------------------------------------
// fused BN1+ReLU + 1x1 conv (128 -> 32): Y[b,o,p] = sum_ci relu(E*sc+sh)*Wc[o,ci]
// ---------------------------------------------------------------------------
__global__ __launch_bounds__(256) void conv_k(const float* __restrict__ Wc) {
    __shared__ float sW[C_ * 128];
    __shared__ float ssc[128], ssh[128];
    for (int i = threadIdx.x; i < C_ * 128; i += 256) sW[i] = Wc[i];
    if (threadIdx.x < 128) {
        ssc[threadIdx.x] = g_stats[320 + threadIdx.x];
        ssh[threadIdx.x] = g_stats[448 + threadIdx.x];
    }
    __syncthreads();

    const int p = blockIdx.x * 256 + threadIdx.x;
    const int b = blockIdx.y;

    float acc[C_];
#pragma unroll
    for (int o = 0; o < C_; o++) acc[o] = 0.0f;

    for (int ci = 0; ci < 128; ci++) {
        const int br = ci >> 5;
        const int c  = ci & 31;
        float v = __bfloat162float(g_E[(((size_t)br * B_ + b) * C_ + c) * HW_ + p]);
        v = fmaxf(v * ssc[ci] + ssh[ci], 0.0f);
#pragma unroll
        for (int o = 0; o < C_; o++) acc[o] += v * sW[o * 128 + ci];
    }

    float* Yp = g_DY + (size_t)(b * C_) * HW_ + p;
#pragma unroll
    for (int o = 0; o < C_; o++) Yp[(size_t)o * HW_] = acc[o];
}

// ---------------------------------------------------------------------------
// BN2 stats over Y
// ---------------------------------------------------------------------------
__global__ __launch_bounds__(256) void stats2_k() {
    const int p = blockIdx.x * 256 + threadIdx.x;
    const int c = blockIdx.y;
    const int b = blockIdx.z;
    const float val = g_DY[(size_t)(b * C_ + c) * HW_ + p];

    float s1 = val;
    float s2 = val * val;
#pragma unroll
    for (int off = 32; off >= 1; off >>= 1) {
        s1 += __shfl_down(s1, off, 64);
        s2 += __shfl_down(s2, off, 64);
    }
    __shared__ float l1[4], l2[4];
    const int lane = threadIdx.x & 63;
    const int wv   = threadIdx.x >> 6;
    if (lane == 0) { l1[wv] = s1; l2[wv] = s2; }
    __syncthreads();
    if (threadIdx.x == 0) {
        atomicAdd(&g_stats[256 + c], l1[0] + l1[1] + l1[2] + l1[3]);
        atomicAdd(&g_stats[288 + c], l2[0] + l2[1] + l2[2] + l2[3]);
    }
}

__global__ void fin2_k(const float* __restrict__ g, const float* __restrict__ b) {
    const int i = threadIdx.x;
    if (i < C_) {
        const float N  = (float)(B_ * HW_);
        const float mu = g_stats[256 + i] / N;
        const float va = fmaxf(g_stats[288 + i] / N - mu * mu, 0.0f);
        const float sc = g[i] * rsqrtf(va + EPS_);
        g_stats[576 + i] = sc;
        g_stats[608 + i] = b[i] - mu * sc;
    }
}

// ---------------------------------------------------------------------------
// final: BN2 + ReLU -> FLOAT32 output (reference returns f32!)
// ---------------------------------------------------------------------------
__global__ __launch_bounds__(256) void final_k(float* __restrict__ out) {
    const int p = blockIdx.x * 256 + threadIdx.x;
    const int c = blockIdx.y;
    const int b = blockIdx.z;
    const size_t idx = (size_t)(b * C_ + c) * HW_ + p;
    out[idx] = fmaxf(g_DY[idx] * g_stats[576 + c] + g_stats[608 + c], 0.0f);
}

// ---------------------------------------------------------------------------
extern "C" void kernel_launch(void* const* d_in, const int* in_sizes, int n_in,
                              void* d_out, int out_size, void* d_ws, size_t ws_size,
                              hipStream_t stream) {
    const float* x  = (const float*)d_in[0];
    const float* wd = (const float*)d_in[1];
    const float* we = (const float*)d_in[2];
    const float* gs = (const float*)d_in[3];
    const float* bs = (const float*)d_in[4];
    const float* Wc = (const float*)d_in[5];
    const float* g  = (const float*)d_in[6];
    const float* bb = (const float*)d_in[7];

    zero_k<<<1, 640, 0, stream>>>();

    const dim3 grid(HW_ / 256, C_, B_);
    for (int br = 0; br < 4; br++) {
        dilate_k<<<grid, 256, 0, stream>>>(x, wd, br);
        erode_k<<<grid, 256, 0, stream>>>(we, br);
    }
    fin1_k<<<1, 128, 0, stream>>>(gs, bs);
    conv_k<<<dim3(HW_ / 256, B_), 256, 0, stream>>>(Wc);
    stats2_k<<<grid, 256, 0, stream>>>();
    fin2_k<<<1, 32, 0, stream>>>(g, bb);
    final_k<<<grid, 256, 0, stream>>>((float*)d_out);
}

// Round 5
// 239.688 us; speedup vs baseline: 3.6595x; 3.6595x over previous
//
#include <hip/hip_runtime.h>
#include <hip/hip_bf16.h>

// Problem constants
#define B_   4
#define C_   32
#define H_   192
#define W_   192
#define HW_  (H_ * W_)          // 36864 = 144 * 256 = 36 * 1024
#define EPS_ 1e-5f

// BETA/ln2 and ln2/BETA (logsumexp in base 2 for the HW exp2/log2 pipe)
#define SCALE_IN  21.640425613334453f
#define SCALE_OUT 0.046209812037329687f

#define NP1 (128 * 4 * 144)     // 73728 partials for BN1 (chan-major: chan*576 + b*144 + pblk)
#define NP2 (32 * 4 * 36)       // 4608 partials for BN2  (chan-major: c*144 + b*36 + pblk)

// ---------------------------------------------------------------------------
// Module-global scratch (no d_ws dependence). No atomics anywhere:
// every block writes partial sums to its own slot; fin kernels reduce.
//   g_stats[0..127] sc1   [128..255] sh1   [256..287] sc2   [288..319] sh2
// ---------------------------------------------------------------------------
__device__ float          g_stats[320];
__device__ float          g_p1[2 * NP1];                    // sum | sq
__device__ float          g_p2[2 * NP2];                    // sum | sq
__device__ __hip_bfloat16 g_E[(size_t)4 * B_ * C_ * HW_];   // 37.75 MB
__device__ float          g_DY[(size_t)B_ * C_ * HW_];      // 18.87 MB (D then Y)

// ---------------------------------------------------------------------------
// soft dilate: D[b,c,p] = LSE_k( beta*(x_tap_k + wd_k) ) / beta
// ---------------------------------------------------------------------------
__global__ __launch_bounds__(256) void dilate_k(const float* __restrict__ x,
                                                const float* __restrict__ wd,
                                                int branch) {
    const int d = branch + 1;
    const int p = blockIdx.x * 256 + threadIdx.x;     // 0..HW-1 exact
    const int c = blockIdx.y;
    const int b = blockIdx.z;
    const int h = p / W_;
    const int w = p - h * W_;

    const float* xp = x + (size_t)(b * C_ + c) * HW_;
    const float* wt = wd + (size_t)(branch * C_ + c) * 9;

    float t[9];
    float m = -1e30f;
#pragma unroll
    for (int i = 0; i < 3; i++) {
#pragma unroll
        for (int j = 0; j < 3; j++) {
            const int hh = h + (i - 1) * d;
            const int ww = w + (j - 1) * d;
            float xv = 0.0f;
            if (hh >= 0 && hh < H_ && ww >= 0 && ww < W_) xv = xp[hh * W_ + ww];
            const float v = (xv + wt[i * 3 + j]) * SCALE_IN;
            t[i * 3 + j] = v;
            m = fmaxf(m, v);
        }
    }
    float s = 0.0f;
#pragma unroll
    for (int k = 0; k < 9; k++) s += exp2f(t[k] - m);
    g_DY[(size_t)(b * C_ + c) * HW_ + p] = (m + log2f(s)) * SCALE_OUT;
}

// ---------------------------------------------------------------------------
// soft erode: E = -LSE_k( beta*(we_k - D_tap_k) ) / beta, + BN1 block partials
// ---------------------------------------------------------------------------
__global__ __launch_bounds__(256) void erode_k(const float* __restrict__ we,
                                               int branch) {
    const int d = branch + 1;
    const int p = blockIdx.x * 256 + threadIdx.x;
    const int c = blockIdx.y;
    const int b = blockIdx.z;
    const int h = p / W_;
    const int w = p - h * W_;

    const float* Dp = g_DY + (size_t)(b * C_ + c) * HW_;
    const float* wt = we + (size_t)(branch * C_ + c) * 9;

    float t[9];
    float m = -1e30f;
#pragma unroll
    for (int i = 0; i < 3; i++) {
#pragma unroll
        for (int j = 0; j < 3; j++) {
            const int hh = h + (i - 1) * d;
            const int ww = w + (j - 1) * d;
            float dv = 0.0f;
            if (hh >= 0 && hh < H_ && ww >= 0 && ww < W_) dv = Dp[hh * W_ + ww];
            const float v = (wt[i * 3 + j] - dv) * SCALE_IN;
            t[i * 3 + j] = v;
            m = fmaxf(m, v);
        }
    }
    float s = 0.0f;
#pragma unroll
    for (int k = 0; k < 9; k++) s += exp2f(t[k] - m);
    const float val = -(m + log2f(s)) * SCALE_OUT;

    g_E[(((size_t)branch * B_ + b) * C_ + c) * HW_ + p] = __float2bfloat16(val);

    // block partial sum/sumsq -> private slot (no atomics)
    float s1 = val;
    float s2 = val * val;
#pragma unroll
    for (int off = 32; off >= 1; off >>= 1) {
        s1 += __shfl_down(s1, off, 64);
        s2 += __shfl_down(s2, off, 64);
    }
    __shared__ float l1[4], l2[4];
    const int lane = threadIdx.x & 63;
    const int wv   = threadIdx.x >> 6;
    if (lane == 0) { l1[wv] = s1; l2[wv] = s2; }
    __syncthreads();
    if (threadIdx.x == 0) {
        const int slot = (branch * C_ + c) * (B_ * 144) + b * 144 + blockIdx.x;
        g_p1[slot]       = l1[0] + l1[1] + l1[2] + l1[3];
        g_p1[NP1 + slot] = l2[0] + l2[1] + l2[2] + l2[3];
    }
}

// ---------------------------------------------------------------------------
// finalize BN1: reduce 576 partials per channel, compute scale/shift
// grid = 128 blocks (one per channel), 256 threads
// ---------------------------------------------------------------------------
__global__ __launch_bounds__(256) void fin1_k(const float* __restrict__ gs,
                                              const float* __restrict__ bs) {
    const int chan = blockIdx.x;
    const int base = chan * (B_ * 144);
    float s1 = 0.0f, s2 = 0.0f;
    for (int i = threadIdx.x; i < B_ * 144; i += 256) {
        s1 += g_p1[base + i];
        s2 += g_p1[NP1 + base + i];
    }
#pragma unroll
    for (int off = 32; off >= 1; off >>= 1) {
        s1 += __shfl_down(s1, off, 64);
        s2 += __shfl_down(s2, off, 64);
    }
    __shared__ float l1[4], l2[4];
    const int lane = threadIdx.x & 63;
    const int wv   = threadIdx.x >> 6;
    if (lane == 0) { l1[wv] = s1; l2[wv] = s2; }
    __syncthreads();
    if (threadIdx.x == 0) {
        const float S1 = l1[0] + l1[1] + l1[2] + l1[3];
        const float S2 = l2[0] + l2[1] + l2[2] + l2[3];
        const float N  = (float)(B_ * HW_);
        const float mu = S1 / N;
        const float va = fmaxf(S2 / N - mu * mu, 0.0f);
        const float sc = gs[chan] * rsqrtf(va + EPS_);
        g_stats[chan]       = sc;
        g_stats[128 + chan] = bs[chan] - mu * sc;
    }
}

// ---------------------------------------------------------------------------
// fused BN1+ReLU + 1x1 conv (128 -> 32): Y[b,o,p] = sum_ci relu(E*sc+sh)*Wc[o,ci]
// ---------------------------------------------------------------------------
__global__ __launch_bounds__(256) void conv_k(const float* __restrict__ Wc) {
    __shared__ float sW[C_ * 128];
    __shared__ float ssc[128], ssh[128];
    for (int i = threadIdx.x; i < C_ * 128; i += 256) sW[i] = Wc[i];
    if (threadIdx.x < 128) {
        ssc[threadIdx.x] = g_stats[threadIdx.x];
        ssh[threadIdx.x] = g_stats[128 + threadIdx.x];
    }
    __syncthreads();

    const int p = blockIdx.x * 256 + threadIdx.x;
    const int b = blockIdx.y;

    float acc[C_];
#pragma unroll
    for (int o = 0; o < C_; o++) acc[o] = 0.0f;

    for (int ci = 0; ci < 128; ci++) {
        const int br = ci >> 5;
        const int c  = ci & 31;
        float v = __bfloat162float(g_E[(((size_t)br * B_ + b) * C_ + c) * HW_ + p]);
        v = fmaxf(v * ssc[ci] + ssh[ci], 0.0f);
#pragma unroll
        for (int o = 0; o < C_; o++) acc[o] += v * sW[o * 128 + ci];
    }

    float* Yp = g_DY + (size_t)(b * C_) * HW_ + p;
#pragma unroll
    for (int o = 0; o < C_; o++) Yp[(size_t)o * HW_] = acc[o];
}

// ---------------------------------------------------------------------------
// BN2 block partials over Y (float4, no atomics). grid (36, 32, 4)
// ---------------------------------------------------------------------------
__global__ __launch_bounds__(256) void stats2_k() {
    const int c = blockIdx.y;
    const int b = blockIdx.z;
    const size_t base = (size_t)(b * C_ + c) * HW_ + (blockIdx.x * 256 + threadIdx.x) * 4;
    const float4 v = *(const float4*)&g_DY[base];

    float s1 = v.x + v.y + v.z + v.w;
    float s2 = v.x * v.x + v.y * v.y + v.z * v.z + v.w * v.w;
#pragma unroll
    for (int off = 32; off >= 1; off >>= 1) {
        s1 += __shfl_down(s1, off, 64);
        s2 += __shfl_down(s2, off, 64);
    }
    __shared__ float l1[4], l2[4];
    const int lane = threadIdx.x & 63;
    const int wv   = threadIdx.x >> 6;
    if (lane == 0) { l1[wv] = s1; l2[wv] = s2; }
    __syncthreads();
    if (threadIdx.x == 0) {
        const int slot = c * (B_ * 36) + b * 36 + blockIdx.x;
        g_p2[slot]       = l1[0] + l1[1] + l1[2] + l1[3];
        g_p2[NP2 + slot] = l2[0] + l2[1] + l2[2] + l2[3];
    }
}

// ---------------------------------------------------------------------------
// finalize BN2: reduce 144 partials per channel. grid = 32 blocks
// ---------------------------------------------------------------------------
__global__ __launch_bounds__(256) void fin2_k(const float* __restrict__ g,
                                              const float* __restrict__ bb) {
    const int chan = blockIdx.x;
    const int base = chan * (B_ * 36);
    float s1 = 0.0f, s2 = 0.0f;
    if (threadIdx.x < B_ * 36) {
        s1 = g_p2[base + threadIdx.x];
        s2 = g_p2[NP2 + base + threadIdx.x];
    }
#pragma unroll
    for (int off = 32; off >= 1; off >>= 1) {
        s1 += __shfl_down(s1, off, 64);
        s2 += __shfl_down(s2, off, 64);
    }
    __shared__ float l1[4], l2[4];
    const int lane = threadIdx.x & 63;
    const int wv   = threadIdx.x >> 6;
    if (lane == 0) { l1[wv] = s1; l2[wv] = s2; }
    __syncthreads();
    if (threadIdx.x == 0) {
        const float S1 = l1[0] + l1[1] + l1[2] + l1[3];
        const float S2 = l2[0] + l2[1] + l2[2] + l2[3];
        const float N  = (float)(B_ * HW_);
        const float mu = S1 / N;
        const float va = fmaxf(S2 / N - mu * mu, 0.0f);
        const float sc = g[chan] * rsqrtf(va + EPS_);
        g_stats[256 + chan] = sc;
        g_stats[288 + chan] = bb[chan] - mu * sc;
    }
}

// ---------------------------------------------------------------------------
// final: BN2 + ReLU -> f32 out (float4). grid (36, 32, 4)
// ---------------------------------------------------------------------------
__global__ __launch_bounds__(256) void final_k(float* __restrict__ out) {
    const int c = blockIdx.y;
    const int b = blockIdx.z;
    const size_t base = (size_t)(b * C_ + c) * HW_ + (blockIdx.x * 256 + threadIdx.x) * 4;
    const float sc = g_stats[256 + c];
    const float sh = g_stats[288 + c];
    const float4 v = *(const float4*)&g_DY[base];
    float4 r;
    r.x = fmaxf(v.x * sc + sh, 0.0f);
    r.y = fmaxf(v.y * sc + sh, 0.0f);
    r.z = fmaxf(v.z * sc + sh, 0.0f);
    r.w = fmaxf(v.w * sc + sh, 0.0f);
    *(float4*)&out[base] = r;
}

// ---------------------------------------------------------------------------
extern "C" void kernel_launch(void* const* d_in, const int* in_sizes, int n_in,
                              void* d_out, int out_size, void* d_ws, size_t ws_size,
                              hipStream_t stream) {
    const float* x  = (const float*)d_in[0];
    const float* wd = (const float*)d_in[1];
    const float* we = (const float*)d_in[2];
    const float* gs = (const float*)d_in[3];
    const float* bs = (const float*)d_in[4];
    const float* Wc = (const float*)d_in[5];
    const float* g  = (const float*)d_in[6];
    const float* bb = (const float*)d_in[7];

    const dim3 grid(HW_ / 256, C_, B_);
    const dim3 grid4(HW_ / 1024, C_, B_);
    for (int br = 0; br < 4; br++) {
        dilate_k<<<grid, 256, 0, stream>>>(x, wd, br);
        erode_k<<<grid, 256, 0, stream>>>(we, br);
    }
    fin1_k<<<128, 256, 0, stream>>>(gs, bs);
    conv_k<<<dim3(HW_ / 256, B_), 256, 0, stream>>>(Wc);
    stats2_k<<<grid4, 256, 0, stream>>>();
    fin2_k<<<32, 256, 0, stream>>>(g, bb);
    final_k<<<grid4, 256, 0, stream>>>((float*)d_out);
}